// Round 11
// baseline (176.345 us; speedup 1.0000x reference)
//
#include <hip/hip_runtime.h>

typedef unsigned short u16;
typedef __attribute__((ext_vector_type(8))) short short8;
typedef __attribute__((ext_vector_type(4))) short s16x4;
typedef __attribute__((ext_vector_type(4))) float f32x4;
typedef __attribute__((ext_vector_type(16))) float f32x16;
typedef __attribute__((ext_vector_type(4))) unsigned u32x4;

#define S_LEN 2048
#define HID 2048
#define NQH 32
#define NKV 8
#define HD 64
#define QKVN 3072
#define SCLOG2 0.1803368801111204f  /* 0.125 * log2(e) */

__device__ __forceinline__ short f2b(float f){
  unsigned u = __builtin_bit_cast(unsigned, f);
  u += 0x7fffu + ((u >> 16) & 1u);
  return (short)(u >> 16);
}
__device__ __forceinline__ float b2f(u16 v){
  unsigned u = ((unsigned)v) << 16;
  return __builtin_bit_cast(float, u);
}
__device__ __forceinline__ void gll16(const void* g, void* l){
  __builtin_amdgcn_global_load_lds((const __attribute__((address_space(1))) void*)g,
                                   (__attribute__((address_space(3))) void*)l, 16, 0, 0);
}
__device__ __forceinline__ unsigned cvtpk(float a, float b){
  unsigned r;
  asm("v_cvt_pk_bf16_f32 %0, %1, %2" : "=v"(r) : "v"(a), "v"(b));
  return r;
}
__device__ __forceinline__ void pswap(unsigned &a, unsigned &b){
  asm volatile("v_permlane32_swap_b32 %0, %1" : "+v"(a), "+v"(b));
}
__device__ __forceinline__ float ex2(float x){
  float r; asm("v_exp_f32 %0, %1" : "=v"(r) : "v"(x)); return r;
}

// ------- fused fp32->bf16 convert (5 tensors) + RoPE table build --------------
__global__ __launch_bounds__(256) void cvt_all(const float* __restrict__ s0,
                                               const float* __restrict__ s1,
                                               const float* __restrict__ s2,
                                               const float* __restrict__ s3,
                                               const float* __restrict__ s4,
                                               u16* __restrict__ d0, u16* __restrict__ d1,
                                               u16* __restrict__ d2, u16* __restrict__ d3,
                                               u16* __restrict__ d4,
                                               const int* __restrict__ pos,
                                               const float* __restrict__ powers,
                                               float* __restrict__ cost,
                                               float* __restrict__ sint){
  int i = blockIdx.x * 256 + threadIdx.x;
  if (i >= 1835008) {
    int j = i - 1835008;                      // S_LEN*32
    int s = j >> 5, d = j & 31;
    float p = (float)pos[s];
    float w = powers[d];
    float sig = 1.0f / (1.0f + expf(-w));
    float inv = powf(10000.0f, -sig);
    float f = p * inv;
    cost[j] = cosf(f);
    sint[j] = sinf(f);
    return;
  }
  const float* s; u16* d; int off;
  if      (i <  524288){ s = s0; d = d0; off = i; }
  else if (i < 1048576){ s = s1; d = d1; off = i -  524288; }
  else if (i < 1179648){ s = s2; d = d2; off = i - 1048576; }
  else if (i < 1310720){ s = s3; d = d3; off = i - 1179648; }
  else                 { s = s4; d = d4; off = i - 1310720; }
  const float4* s4p = (const float4*)s;
  float4 a = s4p[off*2], b = s4p[off*2+1];
  short8 o = { f2b(a.x), f2b(a.y), f2b(a.z), f2b(a.w),
               f2b(b.x), f2b(b.y), f2b(b.z), f2b(b.w) };
  *(short8*)(d + (size_t)off*8) = o;
}

// ---------------- GEMM: C[M][Ntot] = A[M][K] * B[*][K]^T  (bf16 in) -----------
// Double-buffered + both-sides XOR LDS swizzle. MODE 0: QKV (+RoPE, +q-scale,
// V transposed to vtOut). MODE 1: f32 out.
template<int MODE>
__global__ __launch_bounds__(256) void gemm_bt(const u16* __restrict__ A,
                                               const u16* __restrict__ B0,
                                               const u16* __restrict__ B1,
                                               const u16* __restrict__ B2,
                                               int n1, int n2,
                                               void* __restrict__ Cout,
                                               u16* __restrict__ vtOut,
                                               int M, int Ntot, int K,
                                               const float* __restrict__ cost,
                                               const float* __restrict__ sint){
  __shared__ alignas(16) u16 sA[2][128*64];
  __shared__ alignas(16) u16 sB[2][128*64];
  const int tid = threadIdx.x, lane = tid & 63, wv = tid >> 6;
  const int wr = wv >> 1, wc = wv & 1;
  const int m0 = blockIdx.y * 128, n0 = blockIdx.x * 128;
  const int lr = lane & 15, lg = lane >> 4;

  const u16* B;
  if (n0 < n1)      B = B0 + (size_t)n0 * K;
  else if (n0 < n2) B = B1 + (size_t)(n0 - n1) * K;
  else              B = B2 + (size_t)(n0 - n2) * K;

  const int sRow = tid >> 3;
  const int sCol = ((tid & 7) ^ (sRow & 7)) * 8;   // pre-swizzled source column
  const u16* Arow = A + (size_t)(m0 + sRow)*K + sCol;
  const u16* Brow = B + (size_t)sRow*K + sCol;

  f32x4 acc[4][4] = {};
  const int NT = K >> 6;

  #pragma unroll
  for (int i = 0; i < 4; ++i) {
    gll16(Arow + (size_t)i*32*K, (char*)&sA[0][0] + i*4096 + tid*16);
    gll16(Brow + (size_t)i*32*K, (char*)&sB[0][0] + i*4096 + tid*16);
  }
  __syncthreads();

  for (int t = 0; t < NT; ++t) {
    const int cur = t & 1;
    if (t + 1 < NT) {
      const int kn = (t + 1) << 6;
      #pragma unroll
      for (int i = 0; i < 4; ++i) {
        gll16(Arow + (size_t)i*32*K + kn, (char*)&sA[cur^1][0] + i*4096 + tid*16);
        gll16(Brow + (size_t)i*32*K + kn, (char*)&sB[cur^1][0] + i*4096 + tid*16);
      }
    }
    const char* bA = (const char*)&sA[cur][0];
    const char* bB = (const char*)&sB[cur][0];
    #pragma unroll
    for (int kk = 0; kk < 64; kk += 32) {
      short8 af[4], bfr[4];
      #pragma unroll
      for (int m = 0; m < 4; ++m)
        af[m] = *(const short8*)(bA + (wr*64 + m*16 + lr)*128 + ((((kk>>3) + lg) ^ (lr & 7)) << 4));
      #pragma unroll
      for (int n = 0; n < 4; ++n)
        bfr[n] = *(const short8*)(bB + (wc*64 + n*16 + lr)*128 + ((((kk>>3) + lg) ^ (lr & 7)) << 4));
      #pragma unroll
      for (int m = 0; m < 4; ++m)
        #pragma unroll
        for (int n = 0; n < 4; ++n)
          acc[m][n] = __builtin_amdgcn_mfma_f32_16x16x32_bf16(af[m], bfr[n], acc[m][n], 0, 0, 0);
    }
    asm volatile("s_waitcnt vmcnt(0)" ::: "memory");
    __builtin_amdgcn_s_barrier();
  }

  if (MODE == 0 && n0 >= 2560) {
    #pragma unroll
    for (int n = 0; n < 4; ++n) {
      const int colv = n0 - 2560 + wc*64 + n*16 + lr;
      #pragma unroll
      for (int m = 0; m < 4; ++m) {
        const int row = m0 + wr*64 + m*16 + lg*4;
        s16x4 o = { f2b(acc[m][n][0]), f2b(acc[m][n][1]),
                    f2b(acc[m][n][2]), f2b(acc[m][n][3]) };
        *(s16x4*)&vtOut[(size_t)colv*S_LEN + row] = o;
      }
    }
  } else if (MODE == 0) {
    const float qsc = (n0 < n1) ? SCLOG2 : 1.0f;
    #pragma unroll
    for (int m = 0; m < 4; ++m)
      #pragma unroll
      for (int r = 0; r < 4; ++r) {
        int row = m0 + wr*64 + m*16 + lg*4 + r;
        float c0 = cost[row*32 + lr],      s0 = sint[row*32 + lr];
        float c1 = cost[row*32 + 16 + lr], s1 = sint[row*32 + 16 + lr];
        float x0 = acc[m][0][r], x1 = acc[m][1][r];
        float x2 = acc[m][2][r], x3 = acc[m][3][r];
        float o0 = (x0*c0 - x2*s0)*qsc, o2 = (x2*c0 + x0*s0)*qsc;
        float o1 = (x1*c1 - x3*s1)*qsc, o3 = (x3*c1 + x1*s1)*qsc;
        u16* cp = (u16*)Cout + (size_t)row*Ntot + n0 + wc*64 + lr;
        cp[0]  = (u16)f2b(o0);
        cp[16] = (u16)f2b(o1);
        cp[32] = (u16)f2b(o2);
        cp[48] = (u16)f2b(o3);
      }
  } else {
    #pragma unroll
    for (int m = 0; m < 4; ++m)
      #pragma unroll
      for (int n = 0; n < 4; ++n)
        #pragma unroll
        for (int r = 0; r < 4; ++r) {
          int row = m0 + wr*64 + m*16 + lg*4 + r;
          int col = n0 + wc*64 + n*16 + lr;
          ((float*)Cout)[(size_t)row*Ntot + col] = acc[m][n][r];
        }
  }
}

// ---------------- flash attention: 64 q/wave, split-K <=8 tiles ---------------
// grid (16 chunks-of-128q, 4 slices, 32 heads), block 128 = 2 waves of 64 q.
// Each K/V fragment read feeds BOTH q-sub-tiles (0.5 ds_read per MFMA).
// exp2-raw softmax (scale folded into Q), tree-summed l, in-register P.
// Partial (O,l) additive across slices; bf16 partial O, f32 l.
__global__ __launch_bounds__(128) void flash_attn(const u16* __restrict__ qkv,
                                                  const u16* __restrict__ vt,
                                                  u16* __restrict__ pO,
                                                  float* __restrict__ pL){
  __shared__ alignas(16) u16 sK[2][64*64];
  __shared__ alignas(16) u16 sVT[2][64*64];
  const int tid = threadIdx.x, lane = tid & 63, w = tid >> 6;
  const int c = 15 - blockIdx.x, s = blockIdx.y, h = blockIdx.z, kvh = h >> 2;
  const int ns = (2*c + 9) >> 3;
  if (s >= ns) return;
  const int t0 = s*8;
  const int tmax = 2*c + 2;
  const int t1 = (t0 + 8 < tmax) ? t0 + 8 : tmax;
  const int l5 = lane & 31, hi = lane >> 5;
  const int l8g = lane >> 3, b8 = lane & 7;
  const int colOff = (b8 ^ (l8g & 7)) * 8;    // pre-swizzled source column
  const int q0w = c*128 + w*64;

  // wave w stages rows [32w, 32w+32) of each 64-row K and V^T tile
  const u16* srcK = qkv + (size_t)(32*w + l8g)*QKVN + HID + kvh*HD + colOff;
  const u16* srcV = vt + (size_t)(kvh*HD + 32*w + l8g)*S_LEN + colOff;
  char* dK = (char*)sK  + w*4096;
  char* dV = (char*)sVT + w*4096;

  short8 qf[2][4];
  #pragma unroll
  for (int qs = 0; qs < 2; ++qs)
    #pragma unroll
    for (int cc = 0; cc < 4; ++cc)
      qf[qs][cc] = *(const short8*)&qkv[(size_t)(q0w + qs*32 + l5)*QKVN + h*HD + cc*16 + hi*8];

  f32x16 accO0[2] = {}, accO1[2] = {};     // [db] for qs=0 / qs=1
  float l0 = 0.f, l1 = 0.f;

  // prologue: stage tile t0 into buffer 0
  const int kb0 = t0 * 64;
  #pragma unroll
  for (int i = 0; i < 4; ++i) {
    gll16(srcK + (size_t)(kb0 + 8*i)*QKVN,  dK + i*1024);
    gll16(srcV + kb0 + (size_t)(8*i)*S_LEN, dV + i*1024);
  }

  for (int t = t0; t < t1; ++t) {
    const int kt = t*64, cur = (t - t0) & 1;
    if (t + 1 < t1) {
      const int kn = kt + 64;
      char* nK = dK + (cur^1)*8192;
      char* nV = dV + (cur^1)*8192;
      #pragma unroll
      for (int i = 0; i < 4; ++i) {
        gll16(srcK + (size_t)(kn + 8*i)*QKVN,  nK + i*1024);
        gll16(srcV + kn + (size_t)(8*i)*S_LEN, nV + i*1024);
      }
      asm volatile("s_waitcnt vmcnt(8)" ::: "memory");
    } else {
      asm volatile("s_waitcnt vmcnt(0)" ::: "memory");
    }
    __builtin_amdgcn_s_barrier();

    const char* bK = (const char*)sK  + cur*8192;
    const char* bV = (const char*)sVT + cur*8192;

    short8 pa0[4], pa1[4];
    #pragma unroll
    for (int sub = 0; sub < 2; ++sub) {
      short8 kf[4];
      #pragma unroll
      for (int cc = 0; cc < 4; ++cc)
        kf[cc] = *(const short8*)(bK + (sub*32 + l5)*128 + (((cc*2 + hi) ^ (l5 & 7))*16));

      __builtin_amdgcn_s_setprio(1);
      f32x16 z0 = {}, z1 = {};
      #pragma unroll
      for (int cc = 0; cc < 4; ++cc) {
        z0 = __builtin_amdgcn_mfma_f32_32x32x16_bf16(kf[cc], qf[0][cc], z0, 0, 0, 0);
        z1 = __builtin_amdgcn_mfma_f32_32x32x16_bf16(kf[cc], qf[1][cc], z1, 0, 0, 0);
      }
      __builtin_amdgcn_s_setprio(0);

      // softmax for each q-sub-tile (exp2-raw, tree-summed l)
      #pragma unroll
      for (int qs = 0; qs < 2; ++qs) {
        f32x16& z = qs ? z1 : z0;
        const int qg = q0w + qs*32 + l5;
        const bool masked = (kt + 63 > q0w + qs*32);
        if (masked) {
          #pragma unroll
          for (int r = 0; r < 16; ++r) {
            const int k = kt + sub*32 + (r&3) + 8*(r>>2) + 4*hi;
            float e = ex2(z[r]);
            z[r] = (k > qg) ? 0.f : e;
          }
        } else {
          #pragma unroll
          for (int r = 0; r < 16; ++r) z[r] = ex2(z[r]);
        }
        float s0 = (z[0]+z[1]) + (z[2]+z[3]);
        float s1 = (z[4]+z[5]) + (z[6]+z[7]);
        float s2 = (z[8]+z[9]) + (z[10]+z[11]);
        float s3 = (z[12]+z[13]) + (z[14]+z[15]);
        float ts = (s0+s1) + (s2+s3);
        if (qs) l1 += ts; else l0 += ts;

        unsigned a0 = cvtpk(z[0],  z[1]);
        unsigned c0 = cvtpk(z[2],  z[3]);
        unsigned b0 = cvtpk(z[4],  z[5]);
        unsigned d0 = cvtpk(z[6],  z[7]);
        pswap(a0, b0); pswap(c0, d0);
        u32x4 w0 = {a0, c0, b0, d0};
        unsigned a1 = cvtpk(z[8],  z[9]);
        unsigned c1 = cvtpk(z[10], z[11]);
        unsigned b1 = cvtpk(z[12], z[13]);
        unsigned d1 = cvtpk(z[14], z[15]);
        pswap(a1, b1); pswap(c1, d1);
        u32x4 w1 = {a1, c1, b1, d1};
        if (qs) { pa1[sub*2] = __builtin_bit_cast(short8, w0);
                  pa1[sub*2+1] = __builtin_bit_cast(short8, w1); }
        else    { pa0[sub*2] = __builtin_bit_cast(short8, w0);
                  pa0[sub*2+1] = __builtin_bit_cast(short8, w1); }
      }
    }

    // O^T += V^T @ P^T for both q-sub-tiles (V fragment read once)
    __builtin_amdgcn_s_setprio(1);
    #pragma unroll
    for (int s4 = 0; s4 < 4; ++s4)
      #pragma unroll
      for (int db = 0; db < 2; ++db) {
        short8 vf = *(const short8*)(bV + (db*32 + l5)*128 + (((s4*2 + hi) ^ (l5 & 7))*16));
        accO0[db] = __builtin_amdgcn_mfma_f32_32x32x16_bf16(vf, pa0[s4], accO0[db], 0, 0, 0);
        accO1[db] = __builtin_amdgcn_mfma_f32_32x32x16_bf16(vf, pa1[s4], accO1[db], 0, 0, 0);
      }
    __builtin_amdgcn_s_setprio(0);

    asm volatile("s_waitcnt lgkmcnt(0)" ::: "memory");
    __builtin_amdgcn_s_barrier();
  }

  // epilogue: store bf16 partial O and f32 partial l
  l0 += __shfl_xor(l0, 32);
  l1 += __shfl_xor(l1, 32);
  const int slot = (h*16 + c)*4 + s;
  u16* po = pO + (size_t)slot*128*64;
  #pragma unroll
  for (int db = 0; db < 2; ++db)
    #pragma unroll
    for (int g2 = 0; g2 < 4; ++g2) {
      s16x4 o0 = { f2b(accO0[db][g2*4+0]), f2b(accO0[db][g2*4+1]),
                   f2b(accO0[db][g2*4+2]), f2b(accO0[db][g2*4+3]) };
      *(s16x4*)&po[(size_t)(w*64 + l5)*64 + db*32 + g2*8 + hi*4] = o0;
      s16x4 o1 = { f2b(accO1[db][g2*4+0]), f2b(accO1[db][g2*4+1]),
                   f2b(accO1[db][g2*4+2]), f2b(accO1[db][g2*4+3]) };
      *(s16x4*)&po[(size_t)(w*64 + 32 + l5)*64 + db*32 + g2*8 + hi*4] = o1;
    }
  if (lane < 32) {
    pL[(size_t)slot*128 + w*64 + l5]      = l0;
    pL[(size_t)slot*128 + w*64 + 32 + l5] = l1;
  }
}

// ---------------- combine: sum slices, normalize, emit bf16 -------------------
// one thread per (q, h, 8-d group): 2048*32*8 threads
__global__ __launch_bounds__(256) void combine(const u16* __restrict__ pO,
                                               const float* __restrict__ pL,
                                               u16* __restrict__ attn){
  int i = blockIdx.x * 256 + threadIdx.x;
  int d8 = i & 7, h = (i >> 3) & 31, q = i >> 8;
  int c = q >> 7, row = q & 127;
  int ns = (2*c + 9) >> 3;
  float l = 0.f;
  float acc[8] = {};
  for (int s = 0; s < ns; ++s) {
    int slot = (h*16 + c)*4 + s;
    l += pL[(size_t)slot*128 + row];
    short8 v = *(const short8*)&pO[((size_t)slot*128 + row)*64 + d8*8];
    #pragma unroll
    for (int j = 0; j < 8; ++j) acc[j] += b2f((u16)v[j]);
  }
  const float inv = 1.0f / l;
  short8 o = { f2b(acc[0]*inv), f2b(acc[1]*inv), f2b(acc[2]*inv), f2b(acc[3]*inv),
               f2b(acc[4]*inv), f2b(acc[5]*inv), f2b(acc[6]*inv), f2b(acc[7]*inv) };
  *(short8*)&attn[(size_t)q*HID + h*HD + d8*8] = o;
}

// ---------------- launch ----------------
extern "C" void kernel_launch(void* const* d_in, const int* in_sizes, int n_in,
                              void* d_out, int out_size, void* d_ws, size_t ws_size,
                              hipStream_t stream){
  const float* hs     = (const float*)d_in[0];
  const int*   pos    = (const int*)d_in[1];
  const float* powers = (const float*)d_in[2];
  const float* Wq     = (const float*)d_in[3];
  const float* Wk     = (const float*)d_in[4];
  const float* Wv     = (const float*)d_in[5];
  const float* Wo     = (const float*)d_in[6];
  float* out = (float*)d_out;

  char* ws = (char*)d_ws;
  auto take = [&](size_t bytes){ void* p = ws; ws += (bytes + 255) & ~(size_t)255; return p; };
  u16* hs_b  = (u16*)take((size_t)S_LEN*HID*2);
  u16* wq_b  = (u16*)take((size_t)HID*HID*2);
  u16* wk_b  = (u16*)take((size_t)NKV*HD*HID*2);
  u16* wv_b  = (u16*)take((size_t)NKV*HD*HID*2);
  u16* wo_b  = (u16*)take((size_t)HID*HID*2);
  u16* qkv   = (u16*)take((size_t)S_LEN*QKVN*2);
  u16* vt    = (u16*)take((size_t)NKV*HD*S_LEN*2);
  u16* attnb = (u16*)take((size_t)S_LEN*HID*2);
  float* cost = (float*)take((size_t)S_LEN*32*4);
  float* sint = (float*)take((size_t)S_LEN*32*4);
  u16* pOb   = (u16*)take((size_t)NQH*16*4*128*64*2);   // 32 MB bf16 partials
  float* pL  = (float*)take((size_t)NQH*16*4*128*4);    // 1 MB

  cvt_all<<<7424, 256, 0, stream>>>(hs, Wq, Wk, Wv, Wo,
                                    hs_b, wq_b, wk_b, wv_b, wo_b,
                                    pos, powers, cost, sint);

  // fused QKV projection (+RoPE +q-scale; V written transposed into vt)
  gemm_bt<0><<<dim3(QKVN/128, S_LEN/128), 256, 0, stream>>>(
      hs_b, wq_b, wk_b, wv_b, HID, HID + NKV*HD, qkv, vt,
      S_LEN, QKVN, HID, cost, sint);

  flash_attn<<<dim3(16, 4, NQH), 128, 0, stream>>>(qkv, vt, pOb, pL);
  combine<<<S_LEN*NQH*8/256, 256, 0, stream>>>(pOb, pL, attnb);

  gemm_bt<1><<<dim3(HID/128, S_LEN/128), 256, 0, stream>>>(
      attnb, wo_b, wo_b, wo_b, 1<<28, 1<<29, out, nullptr,
      S_LEN, HID, HID, nullptr, nullptr);
}

// Round 12
// 172.149 us; speedup vs baseline: 1.0244x; 1.0244x over previous
//
#include <hip/hip_runtime.h>

typedef unsigned short u16;
typedef __attribute__((ext_vector_type(8))) short short8;
typedef __attribute__((ext_vector_type(4))) short s16x4;
typedef __attribute__((ext_vector_type(4))) float f32x4;
typedef __attribute__((ext_vector_type(16))) float f32x16;
typedef __attribute__((ext_vector_type(4))) unsigned u32x4;

#define S_LEN 2048
#define HID 2048
#define NQH 32
#define NKV 8
#define HD 64
#define QKVN 3072
#define SCLOG2 0.1803368801111204f  /* 0.125 * log2(e) */

__device__ __forceinline__ short f2b(float f){
  unsigned u = __builtin_bit_cast(unsigned, f);
  u += 0x7fffu + ((u >> 16) & 1u);
  return (short)(u >> 16);
}
__device__ __forceinline__ float b2f(u16 v){
  unsigned u = ((unsigned)v) << 16;
  return __builtin_bit_cast(float, u);
}
__device__ __forceinline__ void gll16(const void* g, void* l){
  __builtin_amdgcn_global_load_lds((const __attribute__((address_space(1))) void*)g,
                                   (__attribute__((address_space(3))) void*)l, 16, 0, 0);
}
__device__ __forceinline__ unsigned cvtpk(float a, float b){
  unsigned r;
  asm("v_cvt_pk_bf16_f32 %0, %1, %2" : "=v"(r) : "v"(a), "v"(b));
  return r;
}
__device__ __forceinline__ void pswap(unsigned &a, unsigned &b){
  asm volatile("v_permlane32_swap_b32 %0, %1" : "+v"(a), "+v"(b));
}
__device__ __forceinline__ float ex2(float x){
  float r; asm("v_exp_f32 %0, %1" : "=v"(r) : "v"(x)); return r;
}

// ------- fused fp32->bf16 convert (5 tensors) + RoPE table build --------------
__global__ __launch_bounds__(256) void cvt_all(const float* __restrict__ s0,
                                               const float* __restrict__ s1,
                                               const float* __restrict__ s2,
                                               const float* __restrict__ s3,
                                               const float* __restrict__ s4,
                                               u16* __restrict__ d0, u16* __restrict__ d1,
                                               u16* __restrict__ d2, u16* __restrict__ d3,
                                               u16* __restrict__ d4,
                                               const int* __restrict__ pos,
                                               const float* __restrict__ powers,
                                               float* __restrict__ cost,
                                               float* __restrict__ sint){
  int i = blockIdx.x * 256 + threadIdx.x;
  if (i >= 1835008) {
    int j = i - 1835008;                      // S_LEN*32
    int s = j >> 5, d = j & 31;
    float p = (float)pos[s];
    float w = powers[d];
    float sig = 1.0f / (1.0f + expf(-w));
    float inv = powf(10000.0f, -sig);
    float f = p * inv;
    cost[j] = cosf(f);
    sint[j] = sinf(f);
    return;
  }
  const float* s; u16* d; int off;
  if      (i <  524288){ s = s0; d = d0; off = i; }
  else if (i < 1048576){ s = s1; d = d1; off = i -  524288; }
  else if (i < 1179648){ s = s2; d = d2; off = i - 1048576; }
  else if (i < 1310720){ s = s3; d = d3; off = i - 1179648; }
  else                 { s = s4; d = d4; off = i - 1310720; }
  const float4* s4p = (const float4*)s;
  float4 a = s4p[off*2], b = s4p[off*2+1];
  short8 o = { f2b(a.x), f2b(a.y), f2b(a.z), f2b(a.w),
               f2b(b.x), f2b(b.y), f2b(b.z), f2b(b.w) };
  *(short8*)(d + (size_t)off*8) = o;
}

// ---------------- GEMM: C[M][Ntot] = A[M][K] * B[*][K]^T  (bf16 in) -----------
// 3-stage LDS pipeline (counted vmcnt(16), never drains mid-loop) +
// both-sides XOR LDS swizzle. MODE 0: QKV (+RoPE, +q-scale, V transposed
// to vtOut). MODE 1: f32 out.
template<int MODE>
__global__ __launch_bounds__(256) void gemm_bt(const u16* __restrict__ A,
                                               const u16* __restrict__ B0,
                                               const u16* __restrict__ B1,
                                               const u16* __restrict__ B2,
                                               int n1, int n2,
                                               void* __restrict__ Cout,
                                               u16* __restrict__ vtOut,
                                               int M, int Ntot, int K,
                                               const float* __restrict__ cost,
                                               const float* __restrict__ sint){
  __shared__ alignas(16) u16 sA[3][128*64];
  __shared__ alignas(16) u16 sB[3][128*64];
  const int tid = threadIdx.x, lane = tid & 63, wv = tid >> 6;
  const int wr = wv >> 1, wc = wv & 1;
  const int m0 = blockIdx.y * 128, n0 = blockIdx.x * 128;
  const int lr = lane & 15, lg = lane >> 4;

  const u16* B;
  if (n0 < n1)      B = B0 + (size_t)n0 * K;
  else if (n0 < n2) B = B1 + (size_t)(n0 - n1) * K;
  else              B = B2 + (size_t)(n0 - n2) * K;

  const int sRow = tid >> 3;
  const int sCol = ((tid & 7) ^ (sRow & 7)) * 8;   // pre-swizzled source column
  const u16* Arow = A + (size_t)(m0 + sRow)*K + sCol;
  const u16* Brow = B + (size_t)sRow*K + sCol;

  f32x4 acc[4][4] = {};
  const int NT = K >> 6;

  // stage tile t into buffer buf (8 gll16 per thread: 4 A + 4 B)
  auto STAGE = [&](int t, int buf){
    const int kn = t << 6;
    #pragma unroll
    for (int i = 0; i < 4; ++i) {
      gll16(Arow + (size_t)i*32*K + kn, (char*)&sA[buf][0] + i*4096 + tid*16);
      gll16(Brow + (size_t)i*32*K + kn, (char*)&sB[buf][0] + i*4096 + tid*16);
    }
  };

  STAGE(0, 0);
  STAGE(1, 1);

  int cur = 0;
  for (int t = 0; t < NT; ++t) {
    if (t + 2 < NT) {
      int wb = cur + 2; if (wb >= 3) wb -= 3;
      STAGE(t + 2, wb);
      asm volatile("s_waitcnt vmcnt(16)" ::: "memory");   // tile t landed
    } else if (t + 1 < NT) {
      asm volatile("s_waitcnt vmcnt(8)" ::: "memory");
    } else {
      asm volatile("s_waitcnt vmcnt(0)" ::: "memory");
    }
    __builtin_amdgcn_s_barrier();

    const char* bA = (const char*)&sA[cur][0];
    const char* bB = (const char*)&sB[cur][0];
    #pragma unroll
    for (int kk = 0; kk < 64; kk += 32) {
      short8 af[4], bfr[4];
      #pragma unroll
      for (int m = 0; m < 4; ++m)
        af[m] = *(const short8*)(bA + (wr*64 + m*16 + lr)*128 + ((((kk>>3) + lg) ^ (lr & 7)) << 4));
      #pragma unroll
      for (int n = 0; n < 4; ++n)
        bfr[n] = *(const short8*)(bB + (wc*64 + n*16 + lr)*128 + ((((kk>>3) + lg) ^ (lr & 7)) << 4));
      #pragma unroll
      for (int m = 0; m < 4; ++m)
        #pragma unroll
        for (int n = 0; n < 4; ++n)
          acc[m][n] = __builtin_amdgcn_mfma_f32_16x16x32_bf16(af[m], bfr[n], acc[m][n], 0, 0, 0);
    }
    asm volatile("s_waitcnt lgkmcnt(0)" ::: "memory");
    __builtin_amdgcn_s_barrier();   // safe to overwrite buffer read this iter

    if (++cur == 3) cur = 0;
  }

  if (MODE == 0 && n0 >= 2560) {
    #pragma unroll
    for (int n = 0; n < 4; ++n) {
      const int colv = n0 - 2560 + wc*64 + n*16 + lr;
      #pragma unroll
      for (int m = 0; m < 4; ++m) {
        const int row = m0 + wr*64 + m*16 + lg*4;
        s16x4 o = { f2b(acc[m][n][0]), f2b(acc[m][n][1]),
                    f2b(acc[m][n][2]), f2b(acc[m][n][3]) };
        *(s16x4*)&vtOut[(size_t)colv*S_LEN + row] = o;
      }
    }
  } else if (MODE == 0) {
    const float qsc = (n0 < n1) ? SCLOG2 : 1.0f;
    #pragma unroll
    for (int m = 0; m < 4; ++m)
      #pragma unroll
      for (int r = 0; r < 4; ++r) {
        int row = m0 + wr*64 + m*16 + lg*4 + r;
        float c0 = cost[row*32 + lr],      s0 = sint[row*32 + lr];
        float c1 = cost[row*32 + 16 + lr], s1 = sint[row*32 + 16 + lr];
        float x0 = acc[m][0][r], x1 = acc[m][1][r];
        float x2 = acc[m][2][r], x3 = acc[m][3][r];
        float o0 = (x0*c0 - x2*s0)*qsc, o2 = (x2*c0 + x0*s0)*qsc;
        float o1 = (x1*c1 - x3*s1)*qsc, o3 = (x3*c1 + x1*s1)*qsc;
        u16* cp = (u16*)Cout + (size_t)row*Ntot + n0 + wc*64 + lr;
        cp[0]  = (u16)f2b(o0);
        cp[16] = (u16)f2b(o1);
        cp[32] = (u16)f2b(o2);
        cp[48] = (u16)f2b(o3);
      }
  } else {
    #pragma unroll
    for (int m = 0; m < 4; ++m)
      #pragma unroll
      for (int n = 0; n < 4; ++n)
        #pragma unroll
        for (int r = 0; r < 4; ++r) {
          int row = m0 + wr*64 + m*16 + lg*4 + r;
          int col = n0 + wc*64 + n*16 + lr;
          ((float*)Cout)[(size_t)row*Ntot + col] = acc[m][n][r];
        }
  }
}

// ---------------- flash attention: 4 waves/block, 32x32, NO max-tracking ------
// round-8 structure (best measured) + 3-buffer staging with counted vmcnt.
// grid (16 superchunks longest-first, 32 heads), block 256 = 4 waves of 32 q.
// exp2-raw softmax (scale pre-folded into Q), in-register P via
// cvt_pk + permlane32_swap, l per-lane + one final shfl.
__global__ __launch_bounds__(256) void flash_attn(const u16* __restrict__ qkv,
                                                  const u16* __restrict__ vt,
                                                  u16* __restrict__ attn){
  __shared__ alignas(16) u16 sK[3][64*64];
  __shared__ alignas(16) u16 sVT[3][64*64];
  const int tid = threadIdx.x, lane = tid & 63, w = tid >> 6;
  const int h = blockIdx.y, kvh = h >> 2;
  const int chunk = 15 - blockIdx.x;          // longest first
  const int l5 = lane & 31, hi = lane >> 5;
  const int l8g = lane >> 3, b8 = lane & 7;
  const int colOff = (b8 ^ (l8g & 7)) * 8;    // pre-swizzled source column
  const int q0w = chunk*128 + w*32;
  const int qg = q0w + l5;

  // wave w stages rows [16w,16w+16) of each 64-row tile (2 gll16 K + 2 V)
  const u16* srcK = qkv + (size_t)(16*w + l8g)*QKVN + HID + kvh*HD + colOff;
  const u16* srcV = vt + (size_t)(kvh*HD + 16*w + l8g)*S_LEN + colOff;

  auto STAGE = [&](int t, int buf){
    const int kn = t*64;
    char* dK = (char*)&sK[buf][0]  + w*2048;
    char* dV = (char*)&sVT[buf][0] + w*2048;
    gll16(srcK + (size_t)kn*QKVN,       dK);
    gll16(srcK + (size_t)(kn+8)*QKVN,   dK + 1024);
    gll16(srcV + kn,                    dV);
    gll16(srcV + kn + (size_t)8*S_LEN,  dV + 1024);
  };

  short8 qf[4];
  #pragma unroll
  for (int cc = 0; cc < 4; ++cc)
    qf[cc] = *(const short8*)&qkv[(size_t)(q0w + l5)*QKVN + h*HD + cc*16 + hi*8];

  f32x16 accO[2] = {};
  float l_part = 0.f;
  const int nt = 2*chunk + 2;

  STAGE(0, 0);
  if (nt > 1) STAGE(1, 1);

  int cur = 0;
  for (int t = 0; t < nt; ++t) {
    const int kt = t*64;
    if (t + 2 < nt) {
      int wb = cur + 2; if (wb >= 3) wb -= 3;
      STAGE(t + 2, wb);
      asm volatile("s_waitcnt vmcnt(8)" ::: "memory");    // tile t landed
    } else if (t + 1 < nt) {
      asm volatile("s_waitcnt vmcnt(4)" ::: "memory");
    } else {
      asm volatile("s_waitcnt vmcnt(0)" ::: "memory");
    }
    __builtin_amdgcn_s_barrier();

    if (kt <= q0w + 31) {
      const char* bK = (const char*)&sK[cur][0];
      const char* bV = (const char*)&sVT[cur][0];

      // S^T = K @ Q^T (rows k, cols q=lane&31)
      f32x16 st[2];
      __builtin_amdgcn_s_setprio(1);
      #pragma unroll
      for (int sub = 0; sub < 2; ++sub) {
        f32x16 z = {};
        #pragma unroll
        for (int cc = 0; cc < 4; ++cc) {
          short8 kf = *(const short8*)(bK + (sub*32 + l5)*128 + (((cc*2 + hi) ^ (l5 & 7))*16));
          z = __builtin_amdgcn_mfma_f32_32x32x16_bf16(kf, qf[cc], z, 0, 0, 0);
        }
        st[sub] = z;
      }
      __builtin_amdgcn_s_setprio(0);

      // P = exp2(S) (post-exp zeroing on the diagonal tile only)
      if (kt + 63 > q0w) {
        #pragma unroll
        for (int sub = 0; sub < 2; ++sub)
          #pragma unroll
          for (int r = 0; r < 16; ++r) {
            const int k = kt + sub*32 + (r&3) + 8*(r>>2) + 4*hi;
            float e = ex2(st[sub][r]);
            e = (k > qg) ? 0.f : e;
            st[sub][r] = e; l_part += e;
          }
      } else {
        #pragma unroll
        for (int sub = 0; sub < 2; ++sub)
          #pragma unroll
          for (int r = 0; r < 16; ++r) {
            const float e = ex2(st[sub][r]);
            st[sub][r] = e; l_part += e;
          }
      }

      // P (f32, crow layout) -> bf16 PV A-fragments, in-register
      short8 pa[4];
      #pragma unroll
      for (int sub = 0; sub < 2; ++sub) {
        unsigned a0 = cvtpk(st[sub][0],  st[sub][1]);
        unsigned c0 = cvtpk(st[sub][2],  st[sub][3]);
        unsigned b0 = cvtpk(st[sub][4],  st[sub][5]);
        unsigned d0 = cvtpk(st[sub][6],  st[sub][7]);
        pswap(a0, b0); pswap(c0, d0);
        u32x4 w0 = {a0, c0, b0, d0};
        pa[sub*2] = __builtin_bit_cast(short8, w0);
        unsigned a1 = cvtpk(st[sub][8],  st[sub][9]);
        unsigned c1 = cvtpk(st[sub][10], st[sub][11]);
        unsigned b1 = cvtpk(st[sub][12], st[sub][13]);
        unsigned d1 = cvtpk(st[sub][14], st[sub][15]);
        pswap(a1, b1); pswap(c1, d1);
        u32x4 w1 = {a1, c1, b1, d1};
        pa[sub*2+1] = __builtin_bit_cast(short8, w1);
      }

      // O^T += V^T @ P^T (rows d, cols q)
      __builtin_amdgcn_s_setprio(1);
      #pragma unroll
      for (int s4 = 0; s4 < 4; ++s4)
        #pragma unroll
        for (int db = 0; db < 2; ++db) {
          short8 vf = *(const short8*)(bV + (db*32 + l5)*128 + (((s4*2 + hi) ^ (l5 & 7))*16));
          accO[db] = __builtin_amdgcn_mfma_f32_32x32x16_bf16(vf, pa[s4], accO[db], 0, 0, 0);
        }
      __builtin_amdgcn_s_setprio(0);
    }

    asm volatile("s_waitcnt lgkmcnt(0)" ::: "memory");
    __builtin_amdgcn_s_barrier();
    if (++cur == 3) cur = 0;
  }

  // epilogue: combine the two half-sums of l, normalize, store
  const float l_run = l_part + __shfl_xor(l_part, 32);
  const float invl = 1.0f / l_run;
  #pragma unroll
  for (int db = 0; db < 2; ++db)
    #pragma unroll
    for (int g2 = 0; g2 < 4; ++g2) {
      s16x4 o = { f2b(accO[db][g2*4+0]*invl), f2b(accO[db][g2*4+1]*invl),
                  f2b(accO[db][g2*4+2]*invl), f2b(accO[db][g2*4+3]*invl) };
      *(s16x4*)&attn[(size_t)(q0w + l5)*HID + h*HD + db*32 + g2*8 + hi*4] = o;
    }
}

// ---------------- launch ----------------
extern "C" void kernel_launch(void* const* d_in, const int* in_sizes, int n_in,
                              void* d_out, int out_size, void* d_ws, size_t ws_size,
                              hipStream_t stream){
  const float* hs     = (const float*)d_in[0];
  const int*   pos    = (const int*)d_in[1];
  const float* powers = (const float*)d_in[2];
  const float* Wq     = (const float*)d_in[3];
  const float* Wk     = (const float*)d_in[4];
  const float* Wv     = (const float*)d_in[5];
  const float* Wo     = (const float*)d_in[6];
  float* out = (float*)d_out;

  char* ws = (char*)d_ws;
  auto take = [&](size_t bytes){ void* p = ws; ws += (bytes + 255) & ~(size_t)255; return p; };
  u16* hs_b  = (u16*)take((size_t)S_LEN*HID*2);
  u16* wq_b  = (u16*)take((size_t)HID*HID*2);
  u16* wk_b  = (u16*)take((size_t)NKV*HD*HID*2);
  u16* wv_b  = (u16*)take((size_t)NKV*HD*HID*2);
  u16* wo_b  = (u16*)take((size_t)HID*HID*2);
  u16* qkv   = (u16*)take((size_t)S_LEN*QKVN*2);
  u16* vt    = (u16*)take((size_t)NKV*HD*S_LEN*2);
  u16* attnb = (u16*)take((size_t)S_LEN*HID*2);
  float* cost = (float*)take((size_t)S_LEN*32*4);
  float* sint = (float*)take((size_t)S_LEN*32*4);

  cvt_all<<<7424, 256, 0, stream>>>(hs, Wq, Wk, Wv, Wo,
                                    hs_b, wq_b, wk_b, wv_b, wo_b,
                                    pos, powers, cost, sint);

  // fused QKV projection (+RoPE +q-scale; V written transposed into vt)
  gemm_bt<0><<<dim3(QKVN/128, S_LEN/128), 256, 0, stream>>>(
      hs_b, wq_b, wk_b, wv_b, HID, HID + NKV*HD, qkv, vt,
      S_LEN, QKVN, HID, cost, sint);

  flash_attn<<<dim3(16, NQH), 256, 0, stream>>>(qkv, vt, attnb);

  gemm_bt<1><<<dim3(HID/128, S_LEN/128), 256, 0, stream>>>(
      attnb, wo_b, wo_b, wo_b, 1<<28, 1<<29, out, nullptr,
      S_LEN, HID, HID, nullptr, nullptr);
}

// Round 13
// 156.438 us; speedup vs baseline: 1.1273x; 1.1004x over previous
//
#include <hip/hip_runtime.h>

typedef unsigned short u16;
typedef __attribute__((ext_vector_type(8))) short short8;
typedef __attribute__((ext_vector_type(4))) short s16x4;
typedef __attribute__((ext_vector_type(4))) float f32x4;
typedef __attribute__((ext_vector_type(16))) float f32x16;
typedef __attribute__((ext_vector_type(4))) unsigned u32x4;

#define S_LEN 2048
#define HID 2048
#define NQH 32
#define NKV 8
#define HD 64
#define QKVN 3072
#define SCLOG2 0.1803368801111204f  /* 0.125 * log2(e) */

__device__ __forceinline__ short f2b(float f){
  unsigned u = __builtin_bit_cast(unsigned, f);
  u += 0x7fffu + ((u >> 16) & 1u);
  return (short)(u >> 16);
}
__device__ __forceinline__ float b2f(u16 v){
  unsigned u = ((unsigned)v) << 16;
  return __builtin_bit_cast(float, u);
}
__device__ __forceinline__ void gll16(const void* g, void* l){
  __builtin_amdgcn_global_load_lds((const __attribute__((address_space(1))) void*)g,
                                   (__attribute__((address_space(3))) void*)l, 16, 0, 0);
}
__device__ __forceinline__ unsigned cvtpk(float a, float b){
  unsigned r;
  asm("v_cvt_pk_bf16_f32 %0, %1, %2" : "=v"(r) : "v"(a), "v"(b));
  return r;
}
__device__ __forceinline__ void pswap(unsigned &a, unsigned &b){
  asm volatile("v_permlane32_swap_b32 %0, %1" : "+v"(a), "+v"(b));
}
__device__ __forceinline__ float ex2(float x){
  float r; asm("v_exp_f32 %0, %1" : "=v"(r) : "v"(x)); return r;
}

// ------- fused fp32->bf16 convert (5 tensors) + RoPE table build --------------
__global__ __launch_bounds__(256) void cvt_all(const float* __restrict__ s0,
                                               const float* __restrict__ s1,
                                               const float* __restrict__ s2,
                                               const float* __restrict__ s3,
                                               const float* __restrict__ s4,
                                               u16* __restrict__ d0, u16* __restrict__ d1,
                                               u16* __restrict__ d2, u16* __restrict__ d3,
                                               u16* __restrict__ d4,
                                               const int* __restrict__ pos,
                                               const float* __restrict__ powers,
                                               float* __restrict__ cost,
                                               float* __restrict__ sint){
  int i = blockIdx.x * 256 + threadIdx.x;
  if (i >= 1835008) {
    int j = i - 1835008;                      // S_LEN*32
    int s = j >> 5, d = j & 31;
    float p = (float)pos[s];
    float w = powers[d];
    float sig = 1.0f / (1.0f + expf(-w));
    float inv = powf(10000.0f, -sig);
    float f = p * inv;
    cost[j] = cosf(f);
    sint[j] = sinf(f);
    return;
  }
  const float* s; u16* d; int off;
  if      (i <  524288){ s = s0; d = d0; off = i; }
  else if (i < 1048576){ s = s1; d = d1; off = i -  524288; }
  else if (i < 1179648){ s = s2; d = d2; off = i - 1048576; }
  else if (i < 1310720){ s = s3; d = d3; off = i - 1179648; }
  else                 { s = s4; d = d4; off = i - 1310720; }
  const float4* s4p = (const float4*)s;
  float4 a = s4p[off*2], b = s4p[off*2+1];
  short8 o = { f2b(a.x), f2b(a.y), f2b(a.z), f2b(a.w),
               f2b(b.x), f2b(b.y), f2b(b.z), f2b(b.w) };
  *(short8*)(d + (size_t)off*8) = o;
}

// ---------------- GEMM: C[M][Ntot] = A[M][K_sub] * B[*][K_sub]^T  (bf16 in) ---
// Round-8 proven 2-phase double-buffer + both-sides XOR LDS swizzle.
// MODE 0 (QKV): bf16 out; RoPE (+attn-scale on q) cols<2560, V transposed.
// MODE 1 (Wo):  split-K over blockIdx.z, f32 atomicAdd into pre-zeroed out.
template<int MODE>
__global__ __launch_bounds__(256) void gemm_bt(const u16* __restrict__ A,
                                               const u16* __restrict__ B0,
                                               const u16* __restrict__ B1,
                                               const u16* __restrict__ B2,
                                               int n1, int n2,
                                               void* __restrict__ Cout,
                                               u16* __restrict__ vtOut,
                                               int M, int Ntot, int K,
                                               const float* __restrict__ cost,
                                               const float* __restrict__ sint){
  __shared__ alignas(16) u16 sA[2][128*64];
  __shared__ alignas(16) u16 sB[2][128*64];
  const int tid = threadIdx.x, lane = tid & 63, wv = tid >> 6;
  const int wr = wv >> 1, wc = wv & 1;
  const int m0 = blockIdx.y * 128, n0 = blockIdx.x * 128;
  const int lr = lane & 15, lg = lane >> 4;
  const int Ksub = (MODE == 1) ? (K >> 1) : K;
  const int kOff = (MODE == 1) ? blockIdx.z * Ksub : 0;

  const u16* B;
  if (n0 < n1)      B = B0 + (size_t)n0 * K;
  else if (n0 < n2) B = B1 + (size_t)(n0 - n1) * K;
  else              B = B2 + (size_t)(n0 - n2) * K;

  const int sRow = tid >> 3;
  const int sCol = ((tid & 7) ^ (sRow & 7)) * 8;   // pre-swizzled source column
  const u16* Arow = A + (size_t)(m0 + sRow)*K + kOff + sCol;
  const u16* Brow = B + (size_t)sRow*K + kOff + sCol;

  f32x4 acc[4][4] = {};
  const int NT = Ksub >> 6;

  #pragma unroll
  for (int i = 0; i < 4; ++i) {
    gll16(Arow + (size_t)i*32*K, (char*)&sA[0][0] + i*4096 + tid*16);
    gll16(Brow + (size_t)i*32*K, (char*)&sB[0][0] + i*4096 + tid*16);
  }
  __syncthreads();

  for (int t = 0; t < NT; ++t) {
    const int cur = t & 1;
    if (t + 1 < NT) {
      const int kn = (t + 1) << 6;
      #pragma unroll
      for (int i = 0; i < 4; ++i) {
        gll16(Arow + (size_t)i*32*K + kn, (char*)&sA[cur^1][0] + i*4096 + tid*16);
        gll16(Brow + (size_t)i*32*K + kn, (char*)&sB[cur^1][0] + i*4096 + tid*16);
      }
    }
    const char* bA = (const char*)&sA[cur][0];
    const char* bB = (const char*)&sB[cur][0];
    #pragma unroll
    for (int kk = 0; kk < 64; kk += 32) {
      short8 af[4], bfr[4];
      #pragma unroll
      for (int m = 0; m < 4; ++m)
        af[m] = *(const short8*)(bA + (wr*64 + m*16 + lr)*128 + ((((kk>>3) + lg) ^ (lr & 7)) << 4));
      #pragma unroll
      for (int n = 0; n < 4; ++n)
        bfr[n] = *(const short8*)(bB + (wc*64 + n*16 + lr)*128 + ((((kk>>3) + lg) ^ (lr & 7)) << 4));
      #pragma unroll
      for (int m = 0; m < 4; ++m)
        #pragma unroll
        for (int n = 0; n < 4; ++n)
          acc[m][n] = __builtin_amdgcn_mfma_f32_16x16x32_bf16(af[m], bfr[n], acc[m][n], 0, 0, 0);
    }
    asm volatile("s_waitcnt vmcnt(0)" ::: "memory");
    __builtin_amdgcn_s_barrier();
  }

  if (MODE == 0 && n0 >= 2560) {
    #pragma unroll
    for (int n = 0; n < 4; ++n) {
      const int colv = n0 - 2560 + wc*64 + n*16 + lr;
      #pragma unroll
      for (int m = 0; m < 4; ++m) {
        const int row = m0 + wr*64 + m*16 + lg*4;
        s16x4 o = { f2b(acc[m][n][0]), f2b(acc[m][n][1]),
                    f2b(acc[m][n][2]), f2b(acc[m][n][3]) };
        *(s16x4*)&vtOut[(size_t)colv*S_LEN + row] = o;
      }
    }
  } else if (MODE == 0) {
    const float qsc = (n0 < n1) ? SCLOG2 : 1.0f;
    #pragma unroll
    for (int m = 0; m < 4; ++m)
      #pragma unroll
      for (int r = 0; r < 4; ++r) {
        int row = m0 + wr*64 + m*16 + lg*4 + r;
        float c0 = cost[row*32 + lr],      s0 = sint[row*32 + lr];
        float c1 = cost[row*32 + 16 + lr], s1 = sint[row*32 + 16 + lr];
        float x0 = acc[m][0][r], x1 = acc[m][1][r];
        float x2 = acc[m][2][r], x3 = acc[m][3][r];
        float o0 = (x0*c0 - x2*s0)*qsc, o2 = (x2*c0 + x0*s0)*qsc;
        float o1 = (x1*c1 - x3*s1)*qsc, o3 = (x3*c1 + x1*s1)*qsc;
        u16* cp = (u16*)Cout + (size_t)row*Ntot + n0 + wc*64 + lr;
        cp[0]  = (u16)f2b(o0);
        cp[16] = (u16)f2b(o1);
        cp[32] = (u16)f2b(o2);
        cp[48] = (u16)f2b(o3);
      }
  } else {
    // split-K partial: exactly 2 commutative addends per element (deterministic)
    #pragma unroll
    for (int m = 0; m < 4; ++m)
      #pragma unroll
      for (int n = 0; n < 4; ++n)
        #pragma unroll
        for (int r = 0; r < 4; ++r) {
          int row = m0 + wr*64 + m*16 + lg*4 + r;
          int col = n0 + wc*64 + n*16 + lr;
          atomicAdd(&((float*)Cout)[(size_t)row*Ntot + col], acc[m][n][r]);
        }
  }
}

// ---------------- flash attention: round-8 math, single-barrier 3-buf ring ----
// grid (16 superchunks longest-first, 32 heads), block 256 = 4 waves of 32 q.
// Per tile: vmcnt(4) [tile t landed] -> ONE barrier -> STAGE(t+2) -> compute.
// The barrier proves all waves finished reading buf[(t+2)%3] last iteration,
// so no trailing barrier / lgkm drain is needed.
__global__ __launch_bounds__(256) void flash_attn(const u16* __restrict__ qkv,
                                                  const u16* __restrict__ vt,
                                                  u16* __restrict__ attn){
  __shared__ alignas(16) u16 sK[3][64*64];
  __shared__ alignas(16) u16 sVT[3][64*64];
  const int tid = threadIdx.x, lane = tid & 63, w = tid >> 6;
  const int h = blockIdx.y, kvh = h >> 2;
  const int chunk = 15 - blockIdx.x;          // longest first
  const int l5 = lane & 31, hi = lane >> 5;
  const int l8g = lane >> 3, b8 = lane & 7;
  const int colOff = (b8 ^ (l8g & 7)) * 8;    // pre-swizzled source column
  const int q0w = chunk*128 + w*32;
  const int qg = q0w + l5;

  // wave w stages rows [16w,16w+16) of each 64-row tile (2 gll16 K + 2 V)
  const u16* srcK = qkv + (size_t)(16*w + l8g)*QKVN + HID + kvh*HD + colOff;
  const u16* srcV = vt + (size_t)(kvh*HD + 16*w + l8g)*S_LEN + colOff;

  auto STAGE = [&](int t, int buf){
    const int kn = t*64;
    char* dK = (char*)&sK[buf][0]  + w*2048;
    char* dV = (char*)&sVT[buf][0] + w*2048;
    gll16(srcK + (size_t)kn*QKVN,       dK);
    gll16(srcK + (size_t)(kn+8)*QKVN,   dK + 1024);
    gll16(srcV + kn,                    dV);
    gll16(srcV + kn + (size_t)8*S_LEN,  dV + 1024);
  };

  short8 qf[4];
  #pragma unroll
  for (int cc = 0; cc < 4; ++cc)
    qf[cc] = *(const short8*)&qkv[(size_t)(q0w + l5)*QKVN + h*HD + cc*16 + hi*8];

  f32x16 accO[2] = {};
  float l_part = 0.f;
  const int nt = 2*chunk + 2;

  STAGE(0, 0);
  if (nt > 1) STAGE(1, 1);

  int cur = 0;
  for (int t = 0; t < nt; ++t) {
    const int kt = t*64;
    if (t + 1 < nt) {
      asm volatile("s_waitcnt vmcnt(4)" ::: "memory");    // tile t landed
    } else {
      asm volatile("s_waitcnt vmcnt(0)" ::: "memory");
    }
    __builtin_amdgcn_s_barrier();
    if (t + 2 < nt) {
      int wb = cur + 2; if (wb >= 3) wb -= 3;
      STAGE(t + 2, wb);
    }

    if (kt <= q0w + 31) {
      const char* bK = (const char*)&sK[cur][0];
      const char* bV = (const char*)&sVT[cur][0];

      // S^T = K @ Q^T (rows k, cols q=lane&31)
      f32x16 st[2];
      __builtin_amdgcn_s_setprio(1);
      #pragma unroll
      for (int sub = 0; sub < 2; ++sub) {
        f32x16 z = {};
        #pragma unroll
        for (int cc = 0; cc < 4; ++cc) {
          short8 kf = *(const short8*)(bK + (sub*32 + l5)*128 + (((cc*2 + hi) ^ (l5 & 7))*16));
          z = __builtin_amdgcn_mfma_f32_32x32x16_bf16(kf, qf[cc], z, 0, 0, 0);
        }
        st[sub] = z;
      }
      __builtin_amdgcn_s_setprio(0);

      // P = exp2(S) (post-exp zeroing on the diagonal tile only)
      if (kt + 63 > q0w) {
        #pragma unroll
        for (int sub = 0; sub < 2; ++sub)
          #pragma unroll
          for (int r = 0; r < 16; ++r) {
            const int k = kt + sub*32 + (r&3) + 8*(r>>2) + 4*hi;
            float e = ex2(st[sub][r]);
            e = (k > qg) ? 0.f : e;
            st[sub][r] = e; l_part += e;
          }
      } else {
        #pragma unroll
        for (int sub = 0; sub < 2; ++sub)
          #pragma unroll
          for (int r = 0; r < 16; ++r) {
            const float e = ex2(st[sub][r]);
            st[sub][r] = e; l_part += e;
          }
      }

      // P (f32, crow layout) -> bf16 PV A-fragments, in-register
      short8 pa[4];
      #pragma unroll
      for (int sub = 0; sub < 2; ++sub) {
        unsigned a0 = cvtpk(st[sub][0],  st[sub][1]);
        unsigned c0 = cvtpk(st[sub][2],  st[sub][3]);
        unsigned b0 = cvtpk(st[sub][4],  st[sub][5]);
        unsigned d0 = cvtpk(st[sub][6],  st[sub][7]);
        pswap(a0, b0); pswap(c0, d0);
        u32x4 w0 = {a0, c0, b0, d0};
        pa[sub*2] = __builtin_bit_cast(short8, w0);
        unsigned a1 = cvtpk(st[sub][8],  st[sub][9]);
        unsigned c1 = cvtpk(st[sub][10], st[sub][11]);
        unsigned b1 = cvtpk(st[sub][12], st[sub][13]);
        unsigned d1 = cvtpk(st[sub][14], st[sub][15]);
        pswap(a1, b1); pswap(c1, d1);
        u32x4 w1 = {a1, c1, b1, d1};
        pa[sub*2+1] = __builtin_bit_cast(short8, w1);
      }

      // O^T += V^T @ P^T (rows d, cols q)
      __builtin_amdgcn_s_setprio(1);
      #pragma unroll
      for (int s4 = 0; s4 < 4; ++s4)
        #pragma unroll
        for (int db = 0; db < 2; ++db) {
          short8 vf = *(const short8*)(bV + (db*32 + l5)*128 + (((s4*2 + hi) ^ (l5 & 7))*16));
          accO[db] = __builtin_amdgcn_mfma_f32_32x32x16_bf16(vf, pa[s4], accO[db], 0, 0, 0);
        }
      __builtin_amdgcn_s_setprio(0);
    }

    if (++cur == 3) cur = 0;
  }

  // epilogue: combine the two half-sums of l, normalize, store
  const float l_run = l_part + __shfl_xor(l_part, 32);
  const float invl = 1.0f / l_run;
  #pragma unroll
  for (int db = 0; db < 2; ++db)
    #pragma unroll
    for (int g2 = 0; g2 < 4; ++g2) {
      s16x4 o = { f2b(accO[db][g2*4+0]*invl), f2b(accO[db][g2*4+1]*invl),
                  f2b(accO[db][g2*4+2]*invl), f2b(accO[db][g2*4+3]*invl) };
      *(s16x4*)&attn[(size_t)(q0w + l5)*HID + h*HD + db*32 + g2*8 + hi*4] = o;
    }
}

// ---------------- launch ----------------
extern "C" void kernel_launch(void* const* d_in, const int* in_sizes, int n_in,
                              void* d_out, int out_size, void* d_ws, size_t ws_size,
                              hipStream_t stream){
  const float* hs     = (const float*)d_in[0];
  const int*   pos    = (const int*)d_in[1];
  const float* powers = (const float*)d_in[2];
  const float* Wq     = (const float*)d_in[3];
  const float* Wk     = (const float*)d_in[4];
  const float* Wv     = (const float*)d_in[5];
  const float* Wo     = (const float*)d_in[6];
  float* out = (float*)d_out;

  char* ws = (char*)d_ws;
  auto take = [&](size_t bytes){ void* p = ws; ws += (bytes + 255) & ~(size_t)255; return p; };
  u16* hs_b  = (u16*)take((size_t)S_LEN*HID*2);
  u16* wq_b  = (u16*)take((size_t)HID*HID*2);
  u16* wk_b  = (u16*)take((size_t)NKV*HD*HID*2);
  u16* wv_b  = (u16*)take((size_t)NKV*HD*HID*2);
  u16* wo_b  = (u16*)take((size_t)HID*HID*2);
  u16* qkv   = (u16*)take((size_t)S_LEN*QKVN*2);
  u16* vt    = (u16*)take((size_t)NKV*HD*S_LEN*2);
  u16* attnb = (u16*)take((size_t)S_LEN*HID*2);
  float* cost = (float*)take((size_t)S_LEN*32*4);
  float* sint = (float*)take((size_t)S_LEN*32*4);

  // zero the f32 output: Wo GEMM accumulates into it with atomicAdd (split-K2)
  hipMemsetAsync(d_out, 0, (size_t)out_size * 4, stream);

  cvt_all<<<7424, 256, 0, stream>>>(hs, Wq, Wk, Wv, Wo,
                                    hs_b, wq_b, wk_b, wv_b, wo_b,
                                    pos, powers, cost, sint);

  // fused QKV projection (+RoPE +q-scale; V written transposed into vt)
  gemm_bt<0><<<dim3(QKVN/128, S_LEN/128), 256, 0, stream>>>(
      hs_b, wq_b, wk_b, wv_b, HID, HID + NKV*HD, qkv, vt,
      S_LEN, QKVN, HID, cost, sint);

  flash_attn<<<dim3(16, NQH), 256, 0, stream>>>(qkv, vt, attnb);

  gemm_bt<1><<<dim3(HID/128, S_LEN/128, 2), 256, 0, stream>>>(
      attnb, wo_b, wo_b, wo_b, 1<<28, 1<<29, out, nullptr,
      S_LEN, HID, HID, nullptr, nullptr);
}

// Round 14
// 141.349 us; speedup vs baseline: 1.2476x; 1.1068x over previous
//
#include <hip/hip_runtime.h>

typedef unsigned short u16;
typedef __attribute__((ext_vector_type(8))) short short8;
typedef __attribute__((ext_vector_type(4))) short s16x4;
typedef __attribute__((ext_vector_type(4))) float f32x4;
typedef __attribute__((ext_vector_type(16))) float f32x16;
typedef __attribute__((ext_vector_type(4))) unsigned u32x4;

#define S_LEN 2048
#define HID 2048
#define NQH 32
#define NKV 8
#define HD 64
#define QKVN 3072
#define SCLOG2 0.1803368801111204f  /* 0.125 * log2(e) */

__device__ __forceinline__ short f2b(float f){
  unsigned u = __builtin_bit_cast(unsigned, f);
  u += 0x7fffu + ((u >> 16) & 1u);
  return (short)(u >> 16);
}
__device__ __forceinline__ float b2f(u16 v){
  unsigned u = ((unsigned)v) << 16;
  return __builtin_bit_cast(float, u);
}
__device__ __forceinline__ void gll16(const void* g, void* l){
  __builtin_amdgcn_global_load_lds((const __attribute__((address_space(1))) void*)g,
                                   (__attribute__((address_space(3))) void*)l, 16, 0, 0);
}
__device__ __forceinline__ unsigned cvtpk(float a, float b){
  unsigned r;
  asm("v_cvt_pk_bf16_f32 %0, %1, %2" : "=v"(r) : "v"(a), "v"(b));
  return r;
}
__device__ __forceinline__ void pswap(unsigned &a, unsigned &b){
  asm volatile("v_permlane32_swap_b32 %0, %1" : "+v"(a), "+v"(b));
}
__device__ __forceinline__ float ex2(float x){
  float r; asm("v_exp_f32 %0, %1" : "=v"(r) : "v"(x)); return r;
}

// ------- fused fp32->bf16 convert (5 tensors) + RoPE table build --------------
__global__ __launch_bounds__(256) void cvt_all(const float* __restrict__ s0,
                                               const float* __restrict__ s1,
                                               const float* __restrict__ s2,
                                               const float* __restrict__ s3,
                                               const float* __restrict__ s4,
                                               u16* __restrict__ d0, u16* __restrict__ d1,
                                               u16* __restrict__ d2, u16* __restrict__ d3,
                                               u16* __restrict__ d4,
                                               const int* __restrict__ pos,
                                               const float* __restrict__ powers,
                                               float* __restrict__ cost,
                                               float* __restrict__ sint){
  int i = blockIdx.x * 256 + threadIdx.x;
  if (i >= 1835008) {
    int j = i - 1835008;                      // S_LEN*32
    int s = j >> 5, d = j & 31;
    float p = (float)pos[s];
    float w = powers[d];
    float sig = 1.0f / (1.0f + expf(-w));
    float inv = powf(10000.0f, -sig);
    float f = p * inv;
    cost[j] = cosf(f);
    sint[j] = sinf(f);
    return;
  }
  const float* s; u16* d; int off;
  if      (i <  524288){ s = s0; d = d0; off = i; }
  else if (i < 1048576){ s = s1; d = d1; off = i -  524288; }
  else if (i < 1179648){ s = s2; d = d2; off = i - 1048576; }
  else if (i < 1310720){ s = s3; d = d3; off = i - 1179648; }
  else                 { s = s4; d = d4; off = i - 1310720; }
  const float4* s4p = (const float4*)s;
  float4 a = s4p[off*2], b = s4p[off*2+1];
  short8 o = { f2b(a.x), f2b(a.y), f2b(a.z), f2b(a.w),
               f2b(b.x), f2b(b.y), f2b(b.z), f2b(b.w) };
  *(short8*)(d + (size_t)off*8) = o;
}

// ---------------- GEMM: C[M][Ntot] = A[M][K] * B[*][K]^T  (bf16 in) -----------
// Round-8 proven 2-phase double-buffer + both-sides XOR LDS swizzle.
// MODE 0 (QKV): bf16 out; RoPE (+attn-scale on q) cols<2560, V transposed.
// MODE 1 (Wo):  f32 out, plain.
template<int MODE>
__global__ __launch_bounds__(256) void gemm_bt(const u16* __restrict__ A,
                                               const u16* __restrict__ B0,
                                               const u16* __restrict__ B1,
                                               const u16* __restrict__ B2,
                                               int n1, int n2,
                                               void* __restrict__ Cout,
                                               u16* __restrict__ vtOut,
                                               int M, int Ntot, int K,
                                               const float* __restrict__ cost,
                                               const float* __restrict__ sint){
  __shared__ alignas(16) u16 sA[2][128*64];
  __shared__ alignas(16) u16 sB[2][128*64];
  const int tid = threadIdx.x, lane = tid & 63, wv = tid >> 6;
  const int wr = wv >> 1, wc = wv & 1;
  const int m0 = blockIdx.y * 128, n0 = blockIdx.x * 128;
  const int lr = lane & 15, lg = lane >> 4;

  const u16* B;
  if (n0 < n1)      B = B0 + (size_t)n0 * K;
  else if (n0 < n2) B = B1 + (size_t)(n0 - n1) * K;
  else              B = B2 + (size_t)(n0 - n2) * K;

  const int sRow = tid >> 3;
  const int sCol = ((tid & 7) ^ (sRow & 7)) * 8;   // pre-swizzled source column
  const u16* Arow = A + (size_t)(m0 + sRow)*K + sCol;
  const u16* Brow = B + (size_t)sRow*K + sCol;

  f32x4 acc[4][4] = {};
  const int NT = K >> 6;

  #pragma unroll
  for (int i = 0; i < 4; ++i) {
    gll16(Arow + (size_t)i*32*K, (char*)&sA[0][0] + i*4096 + tid*16);
    gll16(Brow + (size_t)i*32*K, (char*)&sB[0][0] + i*4096 + tid*16);
  }
  __syncthreads();

  for (int t = 0; t < NT; ++t) {
    const int cur = t & 1;
    if (t + 1 < NT) {
      const int kn = (t + 1) << 6;
      #pragma unroll
      for (int i = 0; i < 4; ++i) {
        gll16(Arow + (size_t)i*32*K + kn, (char*)&sA[cur^1][0] + i*4096 + tid*16);
        gll16(Brow + (size_t)i*32*K + kn, (char*)&sB[cur^1][0] + i*4096 + tid*16);
      }
    }
    const char* bA = (const char*)&sA[cur][0];
    const char* bB = (const char*)&sB[cur][0];
    #pragma unroll
    for (int kk = 0; kk < 64; kk += 32) {
      short8 af[4], bfr[4];
      #pragma unroll
      for (int m = 0; m < 4; ++m)
        af[m] = *(const short8*)(bA + (wr*64 + m*16 + lr)*128 + ((((kk>>3) + lg) ^ (lr & 7)) << 4));
      #pragma unroll
      for (int n = 0; n < 4; ++n)
        bfr[n] = *(const short8*)(bB + (wc*64 + n*16 + lr)*128 + ((((kk>>3) + lg) ^ (lr & 7)) << 4));
      #pragma unroll
      for (int m = 0; m < 4; ++m)
        #pragma unroll
        for (int n = 0; n < 4; ++n)
          acc[m][n] = __builtin_amdgcn_mfma_f32_16x16x32_bf16(af[m], bfr[n], acc[m][n], 0, 0, 0);
    }
    asm volatile("s_waitcnt vmcnt(0)" ::: "memory");
    __builtin_amdgcn_s_barrier();
  }

  if (MODE == 0 && n0 >= 2560) {
    #pragma unroll
    for (int n = 0; n < 4; ++n) {
      const int colv = n0 - 2560 + wc*64 + n*16 + lr;
      #pragma unroll
      for (int m = 0; m < 4; ++m) {
        const int row = m0 + wr*64 + m*16 + lg*4;
        s16x4 o = { f2b(acc[m][n][0]), f2b(acc[m][n][1]),
                    f2b(acc[m][n][2]), f2b(acc[m][n][3]) };
        *(s16x4*)&vtOut[(size_t)colv*S_LEN + row] = o;
      }
    }
  } else if (MODE == 0) {
    const float qsc = (n0 < n1) ? SCLOG2 : 1.0f;
    #pragma unroll
    for (int m = 0; m < 4; ++m)
      #pragma unroll
      for (int r = 0; r < 4; ++r) {
        int row = m0 + wr*64 + m*16 + lg*4 + r;
        float c0 = cost[row*32 + lr],      s0 = sint[row*32 + lr];
        float c1 = cost[row*32 + 16 + lr], s1 = sint[row*32 + 16 + lr];
        float x0 = acc[m][0][r], x1 = acc[m][1][r];
        float x2 = acc[m][2][r], x3 = acc[m][3][r];
        float o0 = (x0*c0 - x2*s0)*qsc, o2 = (x2*c0 + x0*s0)*qsc;
        float o1 = (x1*c1 - x3*s1)*qsc, o3 = (x3*c1 + x1*s1)*qsc;
        u16* cp = (u16*)Cout + (size_t)row*Ntot + n0 + wc*64 + lr;
        cp[0]  = (u16)f2b(o0);
        cp[16] = (u16)f2b(o1);
        cp[32] = (u16)f2b(o2);
        cp[48] = (u16)f2b(o3);
      }
  } else {
    #pragma unroll
    for (int m = 0; m < 4; ++m)
      #pragma unroll
      for (int n = 0; n < 4; ++n)
        #pragma unroll
        for (int r = 0; r < 4; ++r) {
          int row = m0 + wr*64 + m*16 + lg*4 + r;
          int col = n0 + wc*64 + n*16 + lr;
          ((float*)Cout)[(size_t)row*Ntot + col] = acc[m][n][r];
        }
  }
}

// ---------------- flash attention: complementary-chunk remap, short chains ----
// grid (16, 32) = 512 blocks of 256 thr (4 waves x 32 q). Linear bid remapped
// so blocks bid and bid+256 (which land on the same CU under round-robin
// dispatch) get chunks c and 15-c -> uniform ~36 tiles per CU.
// Per tile: vmcnt(4) -> ONE barrier -> STAGE(t+2, 3-buf ring) -> compute.
// Chains split: QK 2x2-MFMA, PV 2x2-MFMA (accA/accB merged in epilogue),
// l tree-summed. exp2-raw softmax (scale folded into Q), in-register P.
__global__ __launch_bounds__(256) void flash_attn(const u16* __restrict__ qkv,
                                                  const u16* __restrict__ vt,
                                                  u16* __restrict__ attn){
  __shared__ alignas(16) u16 sK[3][64*64];
  __shared__ alignas(16) u16 sVT[3][64*64];
  const int tid = threadIdx.x, lane = tid & 63, w = tid >> 6;
  const int bid = blockIdx.x + (blockIdx.y << 4);
  int chunk, h;
  if (bid < 256) { chunk = 15 - (bid & 15); h = bid >> 4; }
  else           { int b2 = bid - 256; chunk = b2 & 15; h = 16 + (b2 >> 4); }
  const int kvh = h >> 2;
  const int l5 = lane & 31, hi = lane >> 5;
  const int l8g = lane >> 3, b8 = lane & 7;
  const int colOff = (b8 ^ (l8g & 7)) * 8;    // pre-swizzled source column
  const int q0w = chunk*128 + w*32;
  const int qg = q0w + l5;

  // wave w stages rows [16w,16w+16) of each 64-row tile (2 gll16 K + 2 V)
  const u16* srcK = qkv + (size_t)(16*w + l8g)*QKVN + HID + kvh*HD + colOff;
  const u16* srcV = vt + (size_t)(kvh*HD + 16*w + l8g)*S_LEN + colOff;

  auto STAGE = [&](int t, int buf){
    const int kn = t*64;
    char* dK = (char*)&sK[buf][0]  + w*2048;
    char* dV = (char*)&sVT[buf][0] + w*2048;
    gll16(srcK + (size_t)kn*QKVN,       dK);
    gll16(srcK + (size_t)(kn+8)*QKVN,   dK + 1024);
    gll16(srcV + kn,                    dV);
    gll16(srcV + kn + (size_t)8*S_LEN,  dV + 1024);
  };

  short8 qf[4];
  #pragma unroll
  for (int cc = 0; cc < 4; ++cc)
    qf[cc] = *(const short8*)&qkv[(size_t)(q0w + l5)*QKVN + h*HD + cc*16 + hi*8];

  f32x16 accA[2] = {}, accB[2] = {};
  float l_part = 0.f;
  const int nt = 2*chunk + 2;

  STAGE(0, 0);
  if (nt > 1) STAGE(1, 1);

  int cur = 0;
  for (int t = 0; t < nt; ++t) {
    const int kt = t*64;
    if (t + 1 < nt) {
      asm volatile("s_waitcnt vmcnt(4)" ::: "memory");    // tile t landed
    } else {
      asm volatile("s_waitcnt vmcnt(0)" ::: "memory");
    }
    __builtin_amdgcn_s_barrier();
    if (t + 2 < nt) {
      int wb = cur + 2; if (wb >= 3) wb -= 3;
      STAGE(t + 2, wb);
    }

    if (kt <= q0w + 31) {
      const char* bK = (const char*)&sK[cur][0];
      const char* bV = (const char*)&sVT[cur][0];

      // S^T = K @ Q^T (rows k, cols q=lane&31); two independent 2-MFMA chains
      f32x16 st[2];
      __builtin_amdgcn_s_setprio(1);
      #pragma unroll
      for (int sub = 0; sub < 2; ++sub) {
        short8 kf[4];
        #pragma unroll
        for (int cc = 0; cc < 4; ++cc)
          kf[cc] = *(const short8*)(bK + (sub*32 + l5)*128 + (((cc*2 + hi) ^ (l5 & 7))*16));
        f32x16 za = {}, zb = {};
        za = __builtin_amdgcn_mfma_f32_32x32x16_bf16(kf[0], qf[0], za, 0, 0, 0);
        zb = __builtin_amdgcn_mfma_f32_32x32x16_bf16(kf[1], qf[1], zb, 0, 0, 0);
        za = __builtin_amdgcn_mfma_f32_32x32x16_bf16(kf[2], qf[2], za, 0, 0, 0);
        zb = __builtin_amdgcn_mfma_f32_32x32x16_bf16(kf[3], qf[3], zb, 0, 0, 0);
        st[sub] = za + zb;
      }
      __builtin_amdgcn_s_setprio(0);

      // P = exp2(S) (post-exp zeroing on the diagonal tile only), tree-sum l
      #pragma unroll
      for (int sub = 0; sub < 2; ++sub) {
        f32x16& z = st[sub];
        if (kt + 63 > q0w) {
          #pragma unroll
          for (int r = 0; r < 16; ++r) {
            const int k = kt + sub*32 + (r&3) + 8*(r>>2) + 4*hi;
            float e = ex2(z[r]);
            z[r] = (k > qg) ? 0.f : e;
          }
        } else {
          #pragma unroll
          for (int r = 0; r < 16; ++r) z[r] = ex2(z[r]);
        }
        float s0 = (z[0]+z[1]) + (z[2]+z[3]);
        float s1 = (z[4]+z[5]) + (z[6]+z[7]);
        float s2 = (z[8]+z[9]) + (z[10]+z[11]);
        float s3 = (z[12]+z[13]) + (z[14]+z[15]);
        l_part += (s0+s1) + (s2+s3);
      }

      // P (f32, crow layout) -> bf16 PV A-fragments, in-register
      short8 pa[4];
      #pragma unroll
      for (int sub = 0; sub < 2; ++sub) {
        unsigned a0 = cvtpk(st[sub][0],  st[sub][1]);
        unsigned c0 = cvtpk(st[sub][2],  st[sub][3]);
        unsigned b0 = cvtpk(st[sub][4],  st[sub][5]);
        unsigned d0 = cvtpk(st[sub][6],  st[sub][7]);
        pswap(a0, b0); pswap(c0, d0);
        u32x4 w0 = {a0, c0, b0, d0};
        pa[sub*2] = __builtin_bit_cast(short8, w0);
        unsigned a1 = cvtpk(st[sub][8],  st[sub][9]);
        unsigned c1 = cvtpk(st[sub][10], st[sub][11]);
        unsigned b1 = cvtpk(st[sub][12], st[sub][13]);
        unsigned d1 = cvtpk(st[sub][14], st[sub][15]);
        pswap(a1, b1); pswap(c1, d1);
        u32x4 w1 = {a1, c1, b1, d1};
        pa[sub*2+1] = __builtin_bit_cast(short8, w1);
      }

      // O^T += V^T @ P^T (rows d, cols q); two independent chains per db
      __builtin_amdgcn_s_setprio(1);
      #pragma unroll
      for (int s4 = 0; s4 < 4; ++s4)
        #pragma unroll
        for (int db = 0; db < 2; ++db) {
          short8 vf = *(const short8*)(bV + (db*32 + l5)*128 + (((s4*2 + hi) ^ (l5 & 7))*16));
          if (s4 < 2) accA[db] = __builtin_amdgcn_mfma_f32_32x32x16_bf16(vf, pa[s4], accA[db], 0, 0, 0);
          else        accB[db] = __builtin_amdgcn_mfma_f32_32x32x16_bf16(vf, pa[s4], accB[db], 0, 0, 0);
        }
      __builtin_amdgcn_s_setprio(0);
    }

    if (++cur == 3) cur = 0;
  }

  // epilogue: merge split accumulators, combine half-sums of l, normalize
  const float l_run = l_part + __shfl_xor(l_part, 32);
  const float invl = 1.0f / l_run;
  #pragma unroll
  for (int db = 0; db < 2; ++db) {
    f32x16 acc = accA[db] + accB[db];
    #pragma unroll
    for (int g2 = 0; g2 < 4; ++g2) {
      s16x4 o = { f2b(acc[g2*4+0]*invl), f2b(acc[g2*4+1]*invl),
                  f2b(acc[g2*4+2]*invl), f2b(acc[g2*4+3]*invl) };
      *(s16x4*)&attn[(size_t)(q0w + l5)*HID + h*HD + db*32 + g2*8 + hi*4] = o;
    }
  }
}

// ---------------- launch ----------------
extern "C" void kernel_launch(void* const* d_in, const int* in_sizes, int n_in,
                              void* d_out, int out_size, void* d_ws, size_t ws_size,
                              hipStream_t stream){
  const float* hs     = (const float*)d_in[0];
  const int*   pos    = (const int*)d_in[1];
  const float* powers = (const float*)d_in[2];
  const float* Wq     = (const float*)d_in[3];
  const float* Wk     = (const float*)d_in[4];
  const float* Wv     = (const float*)d_in[5];
  const float* Wo     = (const float*)d_in[6];
  float* out = (float*)d_out;

  char* ws = (char*)d_ws;
  auto take = [&](size_t bytes){ void* p = ws; ws += (bytes + 255) & ~(size_t)255; return p; };
  u16* hs_b  = (u16*)take((size_t)S_LEN*HID*2);
  u16* wq_b  = (u16*)take((size_t)HID*HID*2);
  u16* wk_b  = (u16*)take((size_t)NKV*HD*HID*2);
  u16* wv_b  = (u16*)take((size_t)NKV*HD*HID*2);
  u16* wo_b  = (u16*)take((size_t)HID*HID*2);
  u16* qkv   = (u16*)take((size_t)S_LEN*QKVN*2);
  u16* vt    = (u16*)take((size_t)NKV*HD*S_LEN*2);
  u16* attnb = (u16*)take((size_t)S_LEN*HID*2);
  float* cost = (float*)take((size_t)S_LEN*32*4);
  float* sint = (float*)take((size_t)S_LEN*32*4);

  cvt_all<<<7424, 256, 0, stream>>>(hs, Wq, Wk, Wv, Wo,
                                    hs_b, wq_b, wk_b, wv_b, wo_b,
                                    pos, powers, cost, sint);

  // fused QKV projection (+RoPE +q-scale; V written transposed into vt)
  gemm_bt<0><<<dim3(QKVN/128, S_LEN/128), 256, 0, stream>>>(
      hs_b, wq_b, wk_b, wv_b, HID, HID + NKV*HD, qkv, vt,
      S_LEN, QKVN, HID, cost, sint);

  flash_attn<<<dim3(16, NQH), 256, 0, stream>>>(qkv, vt, attnb);

  gemm_bt<1><<<dim3(HID/128, S_LEN/128), 256, 0, stream>>>(
      attnb, wo_b, wo_b, wo_b, 1<<28, 1<<29, out, nullptr,
      S_LEN, HID, HID, nullptr, nullptr);
}